// Round 1
// baseline (658.929 us; speedup 1.0000x reference)
//
#include <hip/hip_runtime.h>
#include <math.h>

#define DIM 1024
#define ROWS 16384
#define SEQ 4096
#define MARGIN 0.006f

typedef __bf16 v8bf __attribute__((ext_vector_type(8)));
typedef float v4f __attribute__((ext_vector_type(4)));

__device__ __forceinline__ unsigned short f2bf(float f){
  unsigned u = __float_as_uint(f);
  u = u + 0x7FFFu + ((u >> 16) & 1u);   // RNE
  return (unsigned short)(u >> 16);
}
__device__ __forceinline__ unsigned f2o(float f){   // orderable uint (monotonic)
  unsigned u = __float_as_uint(f);
  return (u & 0x80000000u) ? ~u : (u | 0x80000000u);
}
__device__ __forceinline__ float o2f(unsigned u){
  unsigned b = (u & 0x80000000u) ? (u ^ 0x80000000u) : ~u;
  return __uint_as_float(b);
}

// ---------------- fp32 -> bf16 convert ----------------
__global__ __launch_bounds__(256) void cvt_k(const float* __restrict__ s,
                                             unsigned short* __restrict__ d, int n){
  int i = (blockIdx.x * 256 + threadIdx.x) * 4;
  if (i + 3 < n){
    float4 f = *(const float4*)(s + i);
    ushort4 o;
    o.x = f2bf(f.x); o.y = f2bf(f.y); o.z = f2bf(f.z); o.w = f2bf(f.w);
    *(ushort4*)(d + i) = o;
  }
}

// ---------------- bf16 GEMM: C(MxN) = A(MxK) @ B(NxK)^T + bias, K=N=1024 ----------------
__global__ __launch_bounds__(256, 2) void gemm_bt(
    const unsigned short* __restrict__ A, const unsigned short* __restrict__ B,
    const float* __restrict__ bias, float* __restrict__ C)
{
  __shared__ unsigned short lA[128 * 32];
  __shared__ unsigned short lB[128 * 32];
  const int t = threadIdx.x;
  const int lane = t & 63, wave = t >> 6;
  const int m0 = blockIdx.y * 128, n0 = blockIdx.x * 128;
  const int wm = (wave >> 1) * 64, wn = (wave & 1) * 64;
  const int ar = lane & 15, aq = lane >> 4;

  v4f acc[4][4];
#pragma unroll
  for (int i = 0; i < 4; i++)
#pragma unroll
    for (int j = 0; j < 4; j++) acc[i][j] = v4f{0.f, 0.f, 0.f, 0.f};

  for (int k0 = 0; k0 < DIM; k0 += 32){
#pragma unroll
    for (int i = 0; i < 2; i++){
      int c = (wave * 2 + i) * 64 + lane;        // 512 16B chunks per tile
      int row = c >> 2, kq = c & 3;
      __builtin_amdgcn_global_load_lds(
        (const __attribute__((address_space(1))) void*)(A + (size_t)(m0 + row) * DIM + k0 + kq * 8),
        (__attribute__((address_space(3))) void*)(&lA[c * 8]), 16, 0, 0);
      __builtin_amdgcn_global_load_lds(
        (const __attribute__((address_space(1))) void*)(B + (size_t)(n0 + row) * DIM + k0 + kq * 8),
        (__attribute__((address_space(3))) void*)(&lB[c * 8]), 16, 0, 0);
    }
    __syncthreads();
    v8bf af[4], bf[4];
#pragma unroll
    for (int i = 0; i < 4; i++){
      af[i] = *(const v8bf*)&lA[(wm + i * 16 + ar) * 32 + aq * 8];
      bf[i] = *(const v8bf*)&lB[(wn + i * 16 + ar) * 32 + aq * 8];
    }
#pragma unroll
    for (int mi = 0; mi < 4; mi++)
#pragma unroll
      for (int ni = 0; ni < 4; ni++)
        acc[mi][ni] = __builtin_amdgcn_mfma_f32_16x16x32_bf16(af[mi], bf[ni], acc[mi][ni], 0, 0, 0);
    __syncthreads();
  }
#pragma unroll
  for (int mi = 0; mi < 4; mi++)
#pragma unroll
    for (int ni = 0; ni < 4; ni++){
      int colg = n0 + wn + ni * 16 + ar;
      float bv = bias ? bias[colg] : 0.f;
#pragma unroll
      for (int rr = 0; rr < 4; rr++){
        int rowg = m0 + wm + mi * 16 + aq * 4 + rr;
        C[(size_t)rowg * DIM + colg] = acc[mi][ni][rr] + bv;
      }
    }
}

// ---------------- top-64 select + exact boundary fixup + xg (bf16 dense) ----------------
__global__ __launch_bounds__(256) void select_k(
  const float* __restrict__ gate_pre, const float* __restrict__ mag_pre,
  const float* __restrict__ x, const float* __restrict__ gW, const float* __restrict__ gb,
  unsigned short* __restrict__ xg)
{
  __shared__ float sv[DIM];
  __shared__ unsigned hist[256];
  __shared__ unsigned sc[8];        // 0:b1 1:b2 2:count_above 3:na 4:namb
  __shared__ int ambIdx[128];
  __shared__ float ambEx[128];
  __shared__ unsigned short row16[DIM];

  const int r = blockIdx.x;
  const int t = threadIdx.x;
  const int lane = t & 63, wave = t >> 6;
  const float* gp = gate_pre + (size_t)r * DIM;

#pragma unroll
  for (int j = 0; j < 4; j++){ int i = t + j * 256; sv[i] = gp[i]; row16[i] = 0; }
  hist[t] = 0;
  if (t < 8) sc[t] = 0;
  __syncthreads();
#pragma unroll
  for (int j = 0; j < 4; j++){ int i = t + j * 256; atomicAdd(&hist[f2o(sv[i]) >> 24], 1u); }
  __syncthreads();
  if (t == 0){
    unsigned cum = 0; unsigned b = 255;
    for (;;){ if (cum + hist[b] >= 64u) break; cum += hist[b]; if (b == 0) break; --b; }
    sc[0] = b; sc[2] = cum;
  }
  __syncthreads();
  unsigned b1 = sc[0], cab = sc[2];
  hist[t] = 0;
  __syncthreads();
#pragma unroll
  for (int j = 0; j < 4; j++){
    int i = t + j * 256; unsigned u = f2o(sv[i]);
    if ((u >> 24) == b1) atomicAdd(&hist[(u >> 16) & 255u], 1u);
  }
  __syncthreads();
  if (t == 0){
    unsigned cum = cab; unsigned b = 255;
    for (;;){ cum += hist[b]; if (cum >= 64u) break; if (b == 0) break; --b; }
    sc[1] = b;
  }
  __syncthreads();
  unsigned Tu = (b1 << 24) | (sc[1] << 16);
  float lo = o2f(Tu) - MARGIN;              // bucket lower edge - margin
  float hi = o2f(Tu + 0x10000u) + MARGIN;   // bucket upper edge + margin
#pragma unroll
  for (int j = 0; j < 4; j++){
    int i = t + j * 256; float v = sv[i];
    if (v > hi) atomicAdd(&sc[3], 1u);                       // certainly in top-64
    else if (v >= lo){ unsigned p = atomicAdd(&sc[4], 1u); if (p < 128u) ambIdx[p] = i; }
  }
  __syncthreads();
  int na = (int)sc[3];
  int namb = (int)sc[4]; if (namb > 128) namb = 128;
  int s = 64 - na;                                           // slots for ambiguous
  const float* xr = x + (size_t)r * DIM;
  for (int i = wave; i < namb; i += 4){                      // fp32-exact recompute (few per row)
    int d = ambIdx[i];
    const float* wr = gW + (size_t)d * DIM;
    float p = 0.f;
    for (int k = lane; k < DIM; k += 64) p += xr[k] * wr[k];
#pragma unroll
    for (int m = 32; m; m >>= 1) p += __shfl_xor(p, m);
    if (lane == 0) ambEx[i] = p + gb[d];
  }
  __syncthreads();
  for (int i = t; i < namb; i += 256){                       // rank, tie-break by lower index
    float e = ambEx[i]; int d = ambIdx[i];
    int rank = 0;
    for (int j = 0; j < namb; j++){
      float ej = ambEx[j]; int dj = ambIdx[j];
      if (ej > e || (ej == e && dj < d)) rank++;
    }
    if (rank < s){
      float m = mag_pre[(size_t)r * DIM + d];
      row16[d] = f2bf((e > 0.f) ? fmaxf(m, 0.f) : 0.f);
    }
  }
#pragma unroll
  for (int j = 0; j < 4; j++){
    int i = t + j * 256; float v = sv[i];
    if (v > hi){
      float m = mag_pre[(size_t)r * DIM + i];
      row16[i] = f2bf((v > 0.f) ? fmaxf(m, 0.f) : 0.f);
    }
  }
  __syncthreads();
  ((uint2*)(xg + (size_t)r * DIM))[t] = ((const uint2*)row16)[t];
}

// ---------------- epilogue: norms, wedge, phase angles ----------------
__global__ __launch_bounds__(256) void epilogue_k(
  const float* __restrict__ q_pre, const float* __restrict__ k_pre,
  const float* __restrict__ p_pre, float* __restrict__ out)
{
  const int r = blockIdx.x;
  const int t = threadIdx.x;
  if ((r & (SEQ - 1)) == 0){ if (t == 0) out[r] = 0.f; return; }
  const float* qc = q_pre + (size_t)r * DIM; const float* qp = qc - DIM;
  const float* kc = k_pre + (size_t)r * DIM; const float* kp = kc - DIM;
  const float* pc = p_pre + (size_t)r * DIM; const float* pp = pc - DIM;
  __shared__ float red[24];
  const int lane = t & 63, wave = t >> 6;

  float vqc[4], vqp[4], vkc[4], vkp[4];
  float aqc = 0.f, aqp = 0.f, akc = 0.f, akp = 0.f;
#pragma unroll
  for (int j = 0; j < 4; j++){
    int i = t + j * 256;
    vqc[j] = qc[i]; vqp[j] = qp[i]; vkc[j] = kc[i]; vkp[j] = kp[i];
    aqc = fmaf(vqc[j], vqc[j], aqc); aqp = fmaf(vqp[j], vqp[j], aqp);
    akc = fmaf(vkc[j], vkc[j], akc); akp = fmaf(vkp[j], vkp[j], akp);
  }
  float dsum = 0.f;
#pragma unroll
  for (int j = 0; j < 2; j++){
    int pr = t + j * 256;
    float2 a = *(const float2*)(pp + 2 * pr);
    float2 b = *(const float2*)(pc + 2 * pr);
    float ia = 1.f / fmaxf(sqrtf(a.x * a.x + a.y * a.y), 1e-12f);
    float ib = 1.f / fmaxf(sqrtf(b.x * b.x + b.y * b.y), 1e-12f);
    float ax = a.x * ia, ay = a.y * ia, bx = b.x * ib, by = b.y * ib;
    float cross = ax * by - ay * bx;
    float dot = fminf(fmaxf(ax * bx + ay * by, -1.f), 1.f);
    dsum += fabsf(atan2f(cross, dot)) * 0.3183098861837907f;
  }
#pragma unroll
  for (int m = 32; m; m >>= 1){
    aqc += __shfl_xor(aqc, m); aqp += __shfl_xor(aqp, m);
    akc += __shfl_xor(akc, m); akp += __shfl_xor(akp, m);
    dsum += __shfl_xor(dsum, m);
  }
  if (lane == 0){
    red[wave] = aqc; red[4 + wave] = aqp; red[8 + wave] = akc;
    red[12 + wave] = akp; red[16 + wave] = dsum;
  }
  __syncthreads();
  float rqc = 1.f / fmaxf(sqrtf(red[0] + red[1] + red[2] + red[3]), 1e-12f);
  float rqp = 1.f / fmaxf(sqrtf(red[4] + red[5] + red[6] + red[7]), 1e-12f);
  float rkc = 1.f / fmaxf(sqrtf(red[8] + red[9] + red[10] + red[11]), 1e-12f);
  float rkp = 1.f / fmaxf(sqrtf(red[12] + red[13] + red[14] + red[15]), 1e-12f);
  float dtot = red[16] + red[17] + red[18] + red[19];
  float tw = 0.f;
#pragma unroll
  for (int j = 0; j < 4; j++){
    float m = (vqc[j] * rqc) * (vkp[j] * rkp) - (vqp[j] * rqp) * (vkc[j] * rkc);
    tw = fmaf(m, m, tw);
  }
#pragma unroll
  for (int m = 32; m; m >>= 1) tw += __shfl_xor(tw, m);
  if (lane == 0) red[20 + wave] = tw;
  __syncthreads();
  if (t == 0){
    float twt = red[20] + red[21] + red[22] + red[23];
    out[r] = 0.5f * tanhf(sqrtf(twt)) + 0.5f * (dtot * (1.f / 512.f));
  }
}

extern "C" void kernel_launch(void* const* d_in, const int* in_sizes, int n_in,
                              void* d_out, int out_size, void* d_ws, size_t ws_size,
                              hipStream_t stream)
{
  const float* x       = (const float*)d_in[0];
  const float* gate_W  = (const float*)d_in[1];
  const float* gate_b  = (const float*)d_in[2];
  const float* mag_W   = (const float*)d_in[3];
  const float* mag_b   = (const float*)d_in[4];
  const float* Wq      = (const float*)d_in[5];
  const float* Wk      = (const float*)d_in[6];
  const float* phase_W = (const float*)d_in[7];
  float* out = (float*)d_out;

  char* ws = (char*)d_ws;
  unsigned short* xbf  = (unsigned short*)ws;                 // 32 MB (reused as xg)
  unsigned short* gWbf = (unsigned short*)(ws + 33554432);
  unsigned short* mWbf = (unsigned short*)(ws + 35651584);
  unsigned short* qWbf = (unsigned short*)(ws + 37748736);
  unsigned short* kWbf = (unsigned short*)(ws + 39845888);
  unsigned short* pWbf = (unsigned short*)(ws + 41943040);
  float* gate_pre = (float*)(ws + 44040192);    // 64 MB (reused as q_pre)
  float* mag_pre  = (float*)(ws + 111149056);   // 64 MB (reused as k_pre)
  float* p_pre    = (float*)(ws + 178257920);   // 64 MB   (total ~234 MB)

  dim3 b256(256);
  cvt_k<<<16384, b256, 0, stream>>>(x, xbf, ROWS * DIM);
  cvt_k<<<1024, b256, 0, stream>>>(gate_W, gWbf, DIM * DIM);
  cvt_k<<<1024, b256, 0, stream>>>(mag_W, mWbf, DIM * DIM);
  cvt_k<<<1024, b256, 0, stream>>>(Wq, qWbf, DIM * DIM);
  cvt_k<<<1024, b256, 0, stream>>>(Wk, kWbf, DIM * DIM);
  cvt_k<<<1024, b256, 0, stream>>>(phase_W, pWbf, DIM * DIM);

  dim3 gg(8, ROWS / 128);
  gemm_bt<<<gg, b256, 0, stream>>>(xbf, gWbf, gate_b, gate_pre);
  gemm_bt<<<gg, b256, 0, stream>>>(xbf, mWbf, mag_b, mag_pre);

  unsigned short* xg = xbf;   // xbf no longer needed
  select_k<<<ROWS, b256, 0, stream>>>(gate_pre, mag_pre, x, gate_W, gate_b, xg);

  gemm_bt<<<gg, b256, 0, stream>>>(xg, qWbf, nullptr, gate_pre);  // q_pre
  gemm_bt<<<gg, b256, 0, stream>>>(xg, kWbf, nullptr, mag_pre);   // k_pre
  gemm_bt<<<gg, b256, 0, stream>>>(xg, pWbf, nullptr, p_pre);

  epilogue_k<<<ROWS, b256, 0, stream>>>(gate_pre, mag_pre, p_pre, out);
}

// Round 2
// 502.480 us; speedup vs baseline: 1.3114x; 1.3114x over previous
//
#include <hip/hip_runtime.h>
#include <math.h>

#define DIM 1024
#define ROWS 16384
#define SEQ 4096
#define MARGIN 0.006f

typedef __bf16 v8bf __attribute__((ext_vector_type(8)));
typedef float v4f __attribute__((ext_vector_type(4)));

__device__ __forceinline__ unsigned short f2bf(float f){
  unsigned u = __float_as_uint(f);
  u = u + 0x7FFFu + ((u >> 16) & 1u);   // RNE
  return (unsigned short)(u >> 16);
}
__device__ __forceinline__ unsigned f2o(float f){   // orderable uint (monotonic)
  unsigned u = __float_as_uint(f);
  return (u & 0x80000000u) ? ~u : (u | 0x80000000u);
}
__device__ __forceinline__ float o2f(unsigned u){
  unsigned b = (u & 0x80000000u) ? (u ^ 0x80000000u) : ~u;
  return __uint_as_float(b);
}

// ---------------- fp32 -> bf16 convert (x) ----------------
__global__ __launch_bounds__(256) void cvt_k(const float* __restrict__ s,
                                             unsigned short* __restrict__ d, int n){
  int i = (blockIdx.x * 256 + threadIdx.x) * 4;
  if (i + 3 < n){
    float4 f = *(const float4*)(s + i);
    ushort4 o;
    o.x = f2bf(f.x); o.y = f2bf(f.y); o.z = f2bf(f.z); o.w = f2bf(f.w);
    *(ushort4*)(d + i) = o;
  }
}

// ---------------- 5 weights -> one stacked bf16 buffer ----------------
__global__ __launch_bounds__(256) void cvt_w(
    const float* __restrict__ w0, const float* __restrict__ w1,
    const float* __restrict__ w2, const float* __restrict__ w3,
    const float* __restrict__ w4, unsigned short* __restrict__ dst){
  const float* srcs[5] = {w0, w1, w2, w3, w4};
  const float* s = srcs[blockIdx.y];
  int i = (blockIdx.x * 256 + threadIdx.x) * 4;
  float4 f = *(const float4*)(s + i);
  ushort4 o;
  o.x = f2bf(f.x); o.y = f2bf(f.y); o.z = f2bf(f.z); o.w = f2bf(f.w);
  *(ushort4*)(dst + ((size_t)blockIdx.y << 20) + i) = o;
}

// ------- bf16 GEMM: A(MxK) @ B(NtotxK)^T, outputs split per 1024 columns -------
__global__ __launch_bounds__(256, 3) void gemm_bt(
    const unsigned short* __restrict__ A, const unsigned short* __restrict__ B,
    const float* __restrict__ bias0, const float* __restrict__ bias1,
    float* __restrict__ C0, float* __restrict__ C1, float* __restrict__ C2)
{
  __shared__ unsigned short lA[128 * 32];
  __shared__ unsigned short lB[128 * 32];
  const int t = threadIdx.x;
  const int lane = t & 63, wave = t >> 6;
  const int m0 = blockIdx.y * 128, n0 = blockIdx.x * 128;
  const int wm = (wave >> 1) * 64, wn = (wave & 1) * 64;
  const int ar = lane & 15, aq = lane >> 4;

  v4f acc[4][4];
#pragma unroll
  for (int i = 0; i < 4; i++)
#pragma unroll
    for (int j = 0; j < 4; j++) acc[i][j] = v4f{0.f, 0.f, 0.f, 0.f};

  for (int k0 = 0; k0 < DIM; k0 += 32){
#pragma unroll
    for (int i = 0; i < 2; i++){
      int c = (wave * 2 + i) * 64 + lane;        // 512 16B chunks per tile
      int row = c >> 2, kq = c & 3;
      __builtin_amdgcn_global_load_lds(
        (const __attribute__((address_space(1))) void*)(A + (size_t)(m0 + row) * DIM + k0 + kq * 8),
        (__attribute__((address_space(3))) void*)(&lA[c * 8]), 16, 0, 0);
      __builtin_amdgcn_global_load_lds(
        (const __attribute__((address_space(1))) void*)(B + (size_t)(n0 + row) * DIM + k0 + kq * 8),
        (__attribute__((address_space(3))) void*)(&lB[c * 8]), 16, 0, 0);
    }
    __syncthreads();
    v8bf af[4], bf[4];
#pragma unroll
    for (int i = 0; i < 4; i++){
      af[i] = *(const v8bf*)&lA[(wm + i * 16 + ar) * 32 + aq * 8];
      bf[i] = *(const v8bf*)&lB[(wn + i * 16 + ar) * 32 + aq * 8];
    }
#pragma unroll
    for (int mi = 0; mi < 4; mi++)
#pragma unroll
      for (int ni = 0; ni < 4; ni++)
        acc[mi][ni] = __builtin_amdgcn_mfma_f32_16x16x32_bf16(af[mi], bf[ni], acc[mi][ni], 0, 0, 0);
    __syncthreads();
  }
#pragma unroll
  for (int mi = 0; mi < 4; mi++)
#pragma unroll
    for (int ni = 0; ni < 4; ni++){
      int colg = n0 + wn + ni * 16 + ar;
      int os = colg >> 10, col = colg & (DIM - 1);
      float* Cp = (os == 0) ? C0 : ((os == 1) ? C1 : C2);
      const float* bp = (os == 0) ? bias0 : ((os == 1) ? bias1 : nullptr);
      float bv = bp ? bp[col] : 0.f;
#pragma unroll
      for (int rr = 0; rr < 4; rr++){
        int rowg = m0 + wm + mi * 16 + aq * 4 + rr;
        Cp[(size_t)rowg * DIM + col] = acc[mi][ni][rr] + bv;
      }
    }
}

// ---------------- top-64 select + exact boundary fixup + xg (bf16 dense) ----------------
__global__ __launch_bounds__(256) void select_k(
  const float* __restrict__ gate_pre, const float* __restrict__ mag_pre,
  const float* __restrict__ x, const float* __restrict__ gW, const float* __restrict__ gb,
  unsigned short* __restrict__ xg)
{
  __shared__ unsigned hist[256];
  __shared__ unsigned sc[4];        // 0:b1 1:b2 2:count_above_b1
  __shared__ int wna[4];
  __shared__ int ambIdx[128];
  __shared__ float ambEx[128];
  __shared__ unsigned short row16[DIM];
  __shared__ float smag[DIM];
  __shared__ float sx[DIM];

  const int r = blockIdx.x;
  const int t = threadIdx.x;
  const int lane = t & 63, wave = t >> 6;

  // P0: load gate/mag/x rows (coalesced float4), init LDS
  float4 v4 = *(const float4*)(gate_pre + (size_t)r * DIM + 4 * t);
  float4 m4 = *(const float4*)(mag_pre  + (size_t)r * DIM + 4 * t);
  float4 x4 = *(const float4*)(x        + (size_t)r * DIM + 4 * t);
  float v[4] = {v4.x, v4.y, v4.z, v4.w};
  float mg[4] = {m4.x, m4.y, m4.z, m4.w};
  smag[4*t] = m4.x; smag[4*t+1] = m4.y; smag[4*t+2] = m4.z; smag[4*t+3] = m4.w;
  sx[4*t] = x4.x; sx[4*t+1] = x4.y; sx[4*t+2] = x4.z; sx[4*t+3] = x4.w;
  { uint2 z; z.x = 0u; z.y = 0u; *(uint2*)&row16[4*t] = z; }
  hist[t] = 0u;
  if (t < 4){ sc[t] = 0u; wna[t] = 0; }
  __syncthreads();

  // P1: level-1 histogram (top 8 bits of orderable uint)
#pragma unroll
  for (int j = 0; j < 4; j++) atomicAdd(&hist[f2o(v[j]) >> 24], 1u);
  __syncthreads();

  // P2: wave0 parallel suffix-scan over 256 bins (4/lane, from top)
  if (wave == 0){
    unsigned c[4];
    unsigned run = 0;
#pragma unroll
    for (int j = 0; j < 4; j++){ run += hist[255 - 4*lane - j]; c[j] = run; }
    unsigned incl = run;
#pragma unroll
    for (int off = 1; off < 64; off <<= 1){
      unsigned nb = __shfl_up(incl, off);
      if (lane >= off) incl += nb;
    }
    unsigned excl = incl - run;
#pragma unroll
    for (int j = 0; j < 4; j++){
      unsigned cum = excl + c[j];
      unsigned prev = (j == 0) ? excl : excl + c[j-1];
      if (cum >= 64u && prev < 64u){ sc[0] = (unsigned)(255 - 4*lane - j); sc[2] = prev; }
    }
  }
  __syncthreads();
  unsigned b1 = sc[0], cab = sc[2];
  hist[t] = 0u;
  __syncthreads();

  // P3: level-2 histogram (bits 16..23 within bucket b1)
#pragma unroll
  for (int j = 0; j < 4; j++){
    unsigned u = f2o(v[j]);
    if ((u >> 24) == b1) atomicAdd(&hist[(u >> 16) & 255u], 1u);
  }
  __syncthreads();

  // P4: wave0 scan with offset cab
  if (wave == 0){
    unsigned c[4];
    unsigned run = 0;
#pragma unroll
    for (int j = 0; j < 4; j++){ run += hist[255 - 4*lane - j]; c[j] = run; }
    unsigned incl = run;
#pragma unroll
    for (int off = 1; off < 64; off <<= 1){
      unsigned nb = __shfl_up(incl, off);
      if (lane >= off) incl += nb;
    }
    unsigned excl = incl - run;
#pragma unroll
    for (int j = 0; j < 4; j++){
      unsigned cum = cab + excl + c[j];
      unsigned prev = cab + ((j == 0) ? excl : excl + c[j-1]);
      if (cum >= 64u && prev < 64u) sc[1] = (unsigned)(255 - 4*lane - j);
    }
  }
  __syncthreads();

  unsigned Tu = (b1 << 24) | (sc[1] << 16);
  float lo = o2f(Tu) - MARGIN;
  float hi = o2f(Tu + 0x10000u) + MARGIN;

  // P5: classify; count certain winners (ballot-free wave reduce), collect ambiguous
  int cnt = 0;
#pragma unroll
  for (int j = 0; j < 4; j++){
    float vv = v[j];
    if (vv > hi) cnt++;
    else if (vv >= lo){
      unsigned p = atomicAdd(&sc[3], 1u);
      if (p < 128u) ambIdx[p] = 4*t + j;
    }
  }
#pragma unroll
  for (int m = 32; m; m >>= 1) cnt += __shfl_xor(cnt, m);
  if (lane == 0) wna[wave] = cnt;
  __syncthreads();
  int na = wna[0] + wna[1] + wna[2] + wna[3];
  int namb = (int)sc[3]; if (namb > 128) namb = 128;
  int s = 64 - na;

  // P6: fp32-exact recompute of ambiguous gate_pre (one wave per candidate)
  for (int i = wave; i < namb; i += 4){
    int d = ambIdx[i];
    const float* wr = gW + (size_t)d * DIM;
    float p = 0.f;
    for (int k = lane; k < DIM; k += 64) p = fmaf(sx[k], wr[k], p);
#pragma unroll
    for (int m = 32; m; m >>= 1) p += __shfl_xor(p, m);
    if (lane == 0) ambEx[i] = p + gb[d];
  }
  __syncthreads();

  // P7: rank ambiguous (tie-break lower index), winners scatter into row16
  for (int i = t; i < namb; i += 256){
    float e = ambEx[i]; int d = ambIdx[i];
    int rank = 0;
    for (int j = 0; j < namb; j++){
      float ej = ambEx[j]; int dj = ambIdx[j];
      if (ej > e || (ej == e && dj < d)) rank++;
    }
    if (rank < s)
      row16[d] = f2bf((e > 0.f) ? fmaxf(smag[d], 0.f) : 0.f);
  }
  __syncthreads();

  // P8: dense merge + coalesced store (certain winners from registers)
  ushort4 o;
  unsigned short* op = (unsigned short*)&o;
#pragma unroll
  for (int j = 0; j < 4; j++){
    if (v[j] > hi) op[j] = f2bf((v[j] > 0.f) ? fmaxf(mg[j], 0.f) : 0.f);
    else           op[j] = row16[4*t + j];
  }
  *(ushort4*)(xg + (size_t)r * DIM + 4 * t) = o;
}

// ---------------- epilogue: norms, wedge, phase angles ----------------
__global__ __launch_bounds__(256) void epilogue_k(
  const float* __restrict__ q_pre, const float* __restrict__ k_pre,
  const float* __restrict__ p_pre, float* __restrict__ out)
{
  const int r = blockIdx.x;
  const int t = threadIdx.x;
  if ((r & (SEQ - 1)) == 0){ if (t == 0) out[r] = 0.f; return; }
  const float* qc = q_pre + (size_t)r * DIM; const float* qp = qc - DIM;
  const float* kc = k_pre + (size_t)r * DIM; const float* kp = kc - DIM;
  const float* pc = p_pre + (size_t)r * DIM; const float* pp = pc - DIM;
  __shared__ float red[24];
  const int lane = t & 63, wave = t >> 6;

  float vqc[4], vqp[4], vkc[4], vkp[4];
  float aqc = 0.f, aqp = 0.f, akc = 0.f, akp = 0.f;
#pragma unroll
  for (int j = 0; j < 4; j++){
    int i = t + j * 256;
    vqc[j] = qc[i]; vqp[j] = qp[i]; vkc[j] = kc[i]; vkp[j] = kp[i];
    aqc = fmaf(vqc[j], vqc[j], aqc); aqp = fmaf(vqp[j], vqp[j], aqp);
    akc = fmaf(vkc[j], vkc[j], akc); akp = fmaf(vkp[j], vkp[j], akp);
  }
  float dsum = 0.f;
#pragma unroll
  for (int j = 0; j < 2; j++){
    int pr = t + j * 256;
    float2 a = *(const float2*)(pp + 2 * pr);
    float2 b = *(const float2*)(pc + 2 * pr);
    float ia = 1.f / fmaxf(sqrtf(a.x * a.x + a.y * a.y), 1e-12f);
    float ib = 1.f / fmaxf(sqrtf(b.x * b.x + b.y * b.y), 1e-12f);
    float ax = a.x * ia, ay = a.y * ia, bx = b.x * ib, by = b.y * ib;
    float cross = ax * by - ay * bx;
    float dot = fminf(fmaxf(ax * bx + ay * by, -1.f), 1.f);
    dsum += fabsf(atan2f(cross, dot)) * 0.3183098861837907f;
  }
#pragma unroll
  for (int m = 32; m; m >>= 1){
    aqc += __shfl_xor(aqc, m); aqp += __shfl_xor(aqp, m);
    akc += __shfl_xor(akc, m); akp += __shfl_xor(akp, m);
    dsum += __shfl_xor(dsum, m);
  }
  if (lane == 0){
    red[wave] = aqc; red[4 + wave] = aqp; red[8 + wave] = akc;
    red[12 + wave] = akp; red[16 + wave] = dsum;
  }
  __syncthreads();
  float rqc = 1.f / fmaxf(sqrtf(red[0] + red[1] + red[2] + red[3]), 1e-12f);
  float rqp = 1.f / fmaxf(sqrtf(red[4] + red[5] + red[6] + red[7]), 1e-12f);
  float rkc = 1.f / fmaxf(sqrtf(red[8] + red[9] + red[10] + red[11]), 1e-12f);
  float rkp = 1.f / fmaxf(sqrtf(red[12] + red[13] + red[14] + red[15]), 1e-12f);
  float dtot = red[16] + red[17] + red[18] + red[19];
  float tw = 0.f;
#pragma unroll
  for (int j = 0; j < 4; j++){
    float m = (vqc[j] * rqc) * (vkp[j] * rkp) - (vqp[j] * rqp) * (vkc[j] * rkc);
    tw = fmaf(m, m, tw);
  }
#pragma unroll
  for (int m = 32; m; m >>= 1) tw += __shfl_xor(tw, m);
  if (lane == 0) red[20 + wave] = tw;
  __syncthreads();
  if (t == 0){
    float twt = red[20] + red[21] + red[22] + red[23];
    out[r] = 0.5f * tanhf(sqrtf(twt)) + 0.5f * (dtot * (1.f / 512.f));
  }
}

extern "C" void kernel_launch(void* const* d_in, const int* in_sizes, int n_in,
                              void* d_out, int out_size, void* d_ws, size_t ws_size,
                              hipStream_t stream)
{
  const float* x       = (const float*)d_in[0];
  const float* gate_W  = (const float*)d_in[1];
  const float* gate_b  = (const float*)d_in[2];
  const float* mag_W   = (const float*)d_in[3];
  const float* mag_b   = (const float*)d_in[4];
  const float* Wq      = (const float*)d_in[5];
  const float* Wk      = (const float*)d_in[6];
  const float* phase_W = (const float*)d_in[7];
  float* out = (float*)d_out;

  char* ws = (char*)d_ws;
  unsigned short* xbf = (unsigned short*)ws;                  // 32 MB (reused as xg)
  unsigned short* wbf = (unsigned short*)(ws + 33554432);     // 10 MB: [gate;mag;q;k;phase]
  float* gate_pre = (float*)(ws + 44040192);    // 64 MB (reused as q_pre)
  float* mag_pre  = (float*)(ws + 111149056);   // 64 MB (reused as k_pre)
  float* p_pre    = (float*)(ws + 178257920);   // 64 MB   (total ~234 MB)

  dim3 b256(256);
  cvt_k<<<16384, b256, 0, stream>>>(x, xbf, ROWS * DIM);
  cvt_w<<<dim3(1024, 5), b256, 0, stream>>>(gate_W, mag_W, Wq, Wk, phase_W, wbf);

  // gate+mag fused GEMM (N=2048)
  gemm_bt<<<dim3(16, 128), b256, 0, stream>>>(xbf, wbf, gate_b, mag_b,
                                              gate_pre, mag_pre, nullptr);

  unsigned short* xg = xbf;   // xbf no longer needed
  select_k<<<ROWS, b256, 0, stream>>>(gate_pre, mag_pre, x, gate_W, gate_b, xg);

  // q+k+phase fused GEMM (N=3072)
  gemm_bt<<<dim3(24, 128), b256, 0, stream>>>(xg, wbf + (2u << 20), nullptr, nullptr,
                                              gate_pre, mag_pre, p_pre);

  epilogue_k<<<ROWS, b256, 0, stream>>>(gate_pre, mag_pre, p_pre, out);
}

// Round 3
// 478.855 us; speedup vs baseline: 1.3760x; 1.0493x over previous
//
#include <hip/hip_runtime.h>
#include <math.h>

#define DIM 1024
#define ROWS 16384
#define SEQ 4096
#define MARGIN 0.006f

typedef __bf16 v8bf __attribute__((ext_vector_type(8)));
typedef float v4f __attribute__((ext_vector_type(4)));

__device__ __forceinline__ unsigned short f2bf(float f){
  unsigned u = __float_as_uint(f);
  u = u + 0x7FFFu + ((u >> 16) & 1u);   // RNE
  return (unsigned short)(u >> 16);
}
__device__ __forceinline__ float bf2f(unsigned short h){
  return __uint_as_float(((unsigned)h) << 16);
}
__device__ __forceinline__ unsigned short relu_bf(unsigned short h){
  return (h & 0x8000u) ? (unsigned short)0 : h;
}
__device__ __forceinline__ unsigned f2o(float f){   // orderable uint (monotonic)
  unsigned u = __float_as_uint(f);
  return (u & 0x80000000u) ? ~u : (u | 0x80000000u);
}
__device__ __forceinline__ float o2f(unsigned u){
  unsigned b = (u & 0x80000000u) ? (u ^ 0x80000000u) : ~u;
  return __uint_as_float(b);
}

// ---------------- fp32 -> bf16 convert (x) ----------------
__global__ __launch_bounds__(256) void cvt_k(const float* __restrict__ s,
                                             unsigned short* __restrict__ d, int n){
  int i = (blockIdx.x * 256 + threadIdx.x) * 4;
  if (i + 3 < n){
    float4 f = *(const float4*)(s + i);
    ushort4 o;
    o.x = f2bf(f.x); o.y = f2bf(f.y); o.z = f2bf(f.z); o.w = f2bf(f.w);
    *(ushort4*)(d + i) = o;
  }
}

// ---------------- 5 weights -> one stacked bf16 buffer ----------------
__global__ __launch_bounds__(256) void cvt_w(
    const float* __restrict__ w0, const float* __restrict__ w1,
    const float* __restrict__ w2, const float* __restrict__ w3,
    const float* __restrict__ w4, unsigned short* __restrict__ dst){
  const float* srcs[5] = {w0, w1, w2, w3, w4};
  const float* s = srcs[blockIdx.y];
  int i = (blockIdx.x * 256 + threadIdx.x) * 4;
  float4 f = *(const float4*)(s + i);
  ushort4 o;
  o.x = f2bf(f.x); o.y = f2bf(f.y); o.z = f2bf(f.z); o.w = f2bf(f.w);
  *(ushort4*)(dst + ((size_t)blockIdx.y << 20) + i) = o;
}

// ------- bf16 GEMM: A(MxK) @ B(NtotxK)^T, outputs split per 1024 columns -------
// bf16mask bit os: output segment os stored as bf16 (ushort), else fp32.
__global__ __launch_bounds__(256, 4) void gemm_bt(
    const unsigned short* __restrict__ A, const unsigned short* __restrict__ B,
    const float* __restrict__ bias0, const float* __restrict__ bias1,
    void* __restrict__ C0, void* __restrict__ C1, void* __restrict__ C2,
    int bf16mask)
{
  __shared__ unsigned short lA[128 * 32];
  __shared__ unsigned short lB[128 * 32];
  const int t = threadIdx.x;
  const int lane = t & 63, wave = t >> 6;
  const int m0 = blockIdx.y * 128, n0 = blockIdx.x * 128;
  const int wm = (wave >> 1) * 64, wn = (wave & 1) * 64;
  const int ar = lane & 15, aq = lane >> 4;

  v4f acc[4][4];
#pragma unroll
  for (int i = 0; i < 4; i++)
#pragma unroll
    for (int j = 0; j < 4; j++) acc[i][j] = v4f{0.f, 0.f, 0.f, 0.f};

  for (int k0 = 0; k0 < DIM; k0 += 32){
#pragma unroll
    for (int i = 0; i < 2; i++){
      int c = (wave * 2 + i) * 64 + lane;        // 512 16B chunks per tile
      int row = c >> 2, kq = c & 3;
      __builtin_amdgcn_global_load_lds(
        (const __attribute__((address_space(1))) void*)(A + (size_t)(m0 + row) * DIM + k0 + kq * 8),
        (__attribute__((address_space(3))) void*)(&lA[c * 8]), 16, 0, 0);
      __builtin_amdgcn_global_load_lds(
        (const __attribute__((address_space(1))) void*)(B + (size_t)(n0 + row) * DIM + k0 + kq * 8),
        (__attribute__((address_space(3))) void*)(&lB[c * 8]), 16, 0, 0);
    }
    __syncthreads();
    v8bf af[4], bf[4];
#pragma unroll
    for (int i = 0; i < 4; i++){
      af[i] = *(const v8bf*)&lA[(wm + i * 16 + ar) * 32 + aq * 8];
      bf[i] = *(const v8bf*)&lB[(wn + i * 16 + ar) * 32 + aq * 8];
    }
#pragma unroll
    for (int mi = 0; mi < 4; mi++)
#pragma unroll
      for (int ni = 0; ni < 4; ni++)
        acc[mi][ni] = __builtin_amdgcn_mfma_f32_16x16x32_bf16(af[mi], bf[ni], acc[mi][ni], 0, 0, 0);
    __syncthreads();
  }

  const int os = n0 >> 10;                       // 1024-aligned segment, block-uniform
  void* Cp = (os == 0) ? C0 : ((os == 1) ? C1 : C2);
  const float* bp = (os == 0) ? bias0 : ((os == 1) ? bias1 : nullptr);
  const bool half_out = ((bf16mask >> os) & 1) != 0;
#pragma unroll
  for (int mi = 0; mi < 4; mi++)
#pragma unroll
    for (int ni = 0; ni < 4; ni++){
      int col = (n0 + wn + ni * 16 + ar) & (DIM - 1);
      float bv = bp ? bp[col] : 0.f;
#pragma unroll
      for (int rr = 0; rr < 4; rr++){
        int rowg = m0 + wm + mi * 16 + aq * 4 + rr;
        float val = acc[mi][ni][rr] + bv;
        if (half_out) ((unsigned short*)Cp)[(size_t)rowg * DIM + col] = f2bf(val);
        else          ((float*)Cp)[(size_t)rowg * DIM + col] = val;
      }
    }
}

// ---------------- top-64 select + exact boundary fixup + xg (bf16 dense) ----------------
__global__ __launch_bounds__(256) void select_k(
  const float* __restrict__ gate_pre, const unsigned short* __restrict__ mag_pre,
  const float* __restrict__ x, const float* __restrict__ gW, const float* __restrict__ gb,
  unsigned short* __restrict__ xg)
{
  __shared__ unsigned hist[4][256];
  __shared__ unsigned sc[4];        // 0:b1 1:b2 2:count_above_b1 3:namb
  __shared__ int wna[4];
  __shared__ int ambIdx[128];
  __shared__ float ambEx[128];
  __shared__ unsigned short row16[DIM];
  __shared__ unsigned short smag[DIM];
  __shared__ float sx[DIM];

  const int r = blockIdx.x;
  const int t = threadIdx.x;
  const int lane = t & 63, wave = t >> 6;

  // P0: load gate/mag/x rows (coalesced), init LDS
  float4 v4 = *(const float4*)(gate_pre + (size_t)r * DIM + 4 * t);
  ushort4 m4 = *(const ushort4*)(mag_pre + (size_t)r * DIM + 4 * t);
  float4 x4 = *(const float4*)(x        + (size_t)r * DIM + 4 * t);
  float v[4] = {v4.x, v4.y, v4.z, v4.w};
  unsigned short mg[4] = {m4.x, m4.y, m4.z, m4.w};
  *(ushort4*)&smag[4*t] = m4;
  sx[4*t] = x4.x; sx[4*t+1] = x4.y; sx[4*t+2] = x4.z; sx[4*t+3] = x4.w;
  { uint2 z; z.x = 0u; z.y = 0u; *(uint2*)&row16[4*t] = z; }
#pragma unroll
  for (int w = 0; w < 4; w++) hist[w][t] = 0u;
  if (t < 4){ sc[t] = 0u; wna[t] = 0; }
  __syncthreads();

  // P1: level-1 histogram (top 8 bits of orderable uint), per-wave split
#pragma unroll
  for (int j = 0; j < 4; j++) atomicAdd(&hist[wave][f2o(v[j]) >> 24], 1u);
  __syncthreads();

  // P2: wave0 parallel suffix-scan over 256 bins (4/lane, from top)
  if (wave == 0){
    unsigned c[4];
    unsigned run = 0;
#pragma unroll
    for (int j = 0; j < 4; j++){
      int b = 255 - 4*lane - j;
      run += hist[0][b] + hist[1][b] + hist[2][b] + hist[3][b];
      c[j] = run;
    }
    unsigned incl = run;
#pragma unroll
    for (int off = 1; off < 64; off <<= 1){
      unsigned nb = __shfl_up(incl, off);
      if (lane >= off) incl += nb;
    }
    unsigned excl = incl - run;
#pragma unroll
    for (int j = 0; j < 4; j++){
      unsigned cum = excl + c[j];
      unsigned prev = (j == 0) ? excl : excl + c[j-1];
      if (cum >= 64u && prev < 64u){ sc[0] = (unsigned)(255 - 4*lane - j); sc[2] = prev; }
    }
  }
  __syncthreads();
  unsigned b1 = sc[0], cab = sc[2];
#pragma unroll
  for (int w = 0; w < 4; w++) hist[w][t] = 0u;
  __syncthreads();

  // P3: level-2 histogram (bits 16..23 within bucket b1)
#pragma unroll
  for (int j = 0; j < 4; j++){
    unsigned u = f2o(v[j]);
    if ((u >> 24) == b1) atomicAdd(&hist[wave][(u >> 16) & 255u], 1u);
  }
  __syncthreads();

  // P4: wave0 scan with offset cab
  if (wave == 0){
    unsigned c[4];
    unsigned run = 0;
#pragma unroll
    for (int j = 0; j < 4; j++){
      int b = 255 - 4*lane - j;
      run += hist[0][b] + hist[1][b] + hist[2][b] + hist[3][b];
      c[j] = run;
    }
    unsigned incl = run;
#pragma unroll
    for (int off = 1; off < 64; off <<= 1){
      unsigned nb = __shfl_up(incl, off);
      if (lane >= off) incl += nb;
    }
    unsigned excl = incl - run;
#pragma unroll
    for (int j = 0; j < 4; j++){
      unsigned cum = cab + excl + c[j];
      unsigned prev = cab + ((j == 0) ? excl : excl + c[j-1]);
      if (cum >= 64u && prev < 64u) sc[1] = (unsigned)(255 - 4*lane - j);
    }
  }
  __syncthreads();

  unsigned Tu = (b1 << 24) | (sc[1] << 16);
  float lo = o2f(Tu) - MARGIN;
  float hi = o2f(Tu + 0x10000u) + MARGIN;

  // P5: classify; count certain winners, collect ambiguous
  int cnt = 0;
#pragma unroll
  for (int j = 0; j < 4; j++){
    float vv = v[j];
    if (vv > hi) cnt++;
    else if (vv >= lo){
      unsigned p = atomicAdd(&sc[3], 1u);
      if (p < 128u) ambIdx[p] = 4*t + j;
    }
  }
#pragma unroll
  for (int m = 32; m; m >>= 1) cnt += __shfl_xor(cnt, m);
  if (lane == 0) wna[wave] = cnt;
  __syncthreads();
  int na = wna[0] + wna[1] + wna[2] + wna[3];
  int namb = (int)sc[3]; if (namb > 128) namb = 128;
  int s = 64 - na;

  // P6: fp32-exact recompute of ambiguous gate_pre (one wave per candidate)
  for (int i = wave; i < namb; i += 4){
    int d = ambIdx[i];
    const float* wr = gW + (size_t)d * DIM;
    float p = 0.f;
    for (int k = lane; k < DIM; k += 64) p = fmaf(sx[k], wr[k], p);
#pragma unroll
    for (int m = 32; m; m >>= 1) p += __shfl_xor(p, m);
    if (lane == 0) ambEx[i] = p + gb[d];
  }
  __syncthreads();

  // P7: rank ambiguous (tie-break lower index), winners scatter into row16
  for (int i = t; i < namb; i += 256){
    float e = ambEx[i]; int d = ambIdx[i];
    int rank = 0;
    for (int j = 0; j < namb; j++){
      float ej = ambEx[j]; int dj = ambIdx[j];
      if (ej > e || (ej == e && dj < d)) rank++;
    }
    if (rank < s)
      row16[d] = (e > 0.f) ? relu_bf(smag[d]) : (unsigned short)0;
  }
  __syncthreads();

  // P8: dense merge + coalesced store (certain winners from registers)
  ushort4 o;
  unsigned short* op = (unsigned short*)&o;
#pragma unroll
  for (int j = 0; j < 4; j++){
    if (v[j] > hi) op[j] = (v[j] > 0.f) ? relu_bf(mg[j]) : (unsigned short)0;
    else           op[j] = row16[4*t + j];
  }
  *(ushort4*)(xg + (size_t)r * DIM + 4 * t) = o;
}

// ---------------- epilogue: norms, wedge, phase angles (bf16 inputs) ----------------
__global__ __launch_bounds__(256) void epilogue_k(
  const unsigned short* __restrict__ q_pre, const unsigned short* __restrict__ k_pre,
  const unsigned short* __restrict__ p_pre, float* __restrict__ out)
{
  const int r = blockIdx.x;
  const int t = threadIdx.x;
  if ((r & (SEQ - 1)) == 0){ if (t == 0) out[r] = 0.f; return; }
  const unsigned short* qc = q_pre + (size_t)r * DIM; const unsigned short* qp = qc - DIM;
  const unsigned short* kc = k_pre + (size_t)r * DIM; const unsigned short* kp = kc - DIM;
  const unsigned short* pc = p_pre + (size_t)r * DIM; const unsigned short* pp = pc - DIM;
  __shared__ float red[24];
  const int lane = t & 63, wave = t >> 6;

  ushort4 uqc = *(const ushort4*)(qc + 4*t), uqp = *(const ushort4*)(qp + 4*t);
  ushort4 ukc = *(const ushort4*)(kc + 4*t), ukp = *(const ushort4*)(kp + 4*t);
  ushort4 upc = *(const ushort4*)(pc + 4*t), upp = *(const ushort4*)(pp + 4*t);
  float vqc[4] = {bf2f(uqc.x), bf2f(uqc.y), bf2f(uqc.z), bf2f(uqc.w)};
  float vqp[4] = {bf2f(uqp.x), bf2f(uqp.y), bf2f(uqp.z), bf2f(uqp.w)};
  float vkc[4] = {bf2f(ukc.x), bf2f(ukc.y), bf2f(ukc.z), bf2f(ukc.w)};
  float vkp[4] = {bf2f(ukp.x), bf2f(ukp.y), bf2f(ukp.z), bf2f(ukp.w)};
  float vpc[4] = {bf2f(upc.x), bf2f(upc.y), bf2f(upc.z), bf2f(upc.w)};
  float vpp[4] = {bf2f(upp.x), bf2f(upp.y), bf2f(upp.z), bf2f(upp.w)};

  float aqc = 0.f, aqp = 0.f, akc = 0.f, akp = 0.f;
#pragma unroll
  for (int j = 0; j < 4; j++){
    aqc = fmaf(vqc[j], vqc[j], aqc); aqp = fmaf(vqp[j], vqp[j], aqp);
    akc = fmaf(vkc[j], vkc[j], akc); akp = fmaf(vkp[j], vkp[j], akp);
  }
  float dsum = 0.f;
#pragma unroll
  for (int j = 0; j < 2; j++){          // two pairs per thread
    float ax = vpp[2*j], ay = vpp[2*j+1], bx = vpc[2*j], by = vpc[2*j+1];
    float ia = 1.f / fmaxf(sqrtf(ax * ax + ay * ay), 1e-12f);
    float ib = 1.f / fmaxf(sqrtf(bx * bx + by * by), 1e-12f);
    ax *= ia; ay *= ia; bx *= ib; by *= ib;
    float cross = ax * by - ay * bx;
    float dot = fminf(fmaxf(ax * bx + ay * by, -1.f), 1.f);
    dsum += fabsf(atan2f(cross, dot)) * 0.3183098861837907f;
  }
#pragma unroll
  for (int m = 32; m; m >>= 1){
    aqc += __shfl_xor(aqc, m); aqp += __shfl_xor(aqp, m);
    akc += __shfl_xor(akc, m); akp += __shfl_xor(akp, m);
    dsum += __shfl_xor(dsum, m);
  }
  if (lane == 0){
    red[wave] = aqc; red[4 + wave] = aqp; red[8 + wave] = akc;
    red[12 + wave] = akp; red[16 + wave] = dsum;
  }
  __syncthreads();
  float rqc = 1.f / fmaxf(sqrtf(red[0] + red[1] + red[2] + red[3]), 1e-12f);
  float rqp = 1.f / fmaxf(sqrtf(red[4] + red[5] + red[6] + red[7]), 1e-12f);
  float rkc = 1.f / fmaxf(sqrtf(red[8] + red[9] + red[10] + red[11]), 1e-12f);
  float rkp = 1.f / fmaxf(sqrtf(red[12] + red[13] + red[14] + red[15]), 1e-12f);
  float dtot = red[16] + red[17] + red[18] + red[19];
  float tw = 0.f;
#pragma unroll
  for (int j = 0; j < 4; j++){
    float m = (vqc[j] * rqc) * (vkp[j] * rkp) - (vqp[j] * rqp) * (vkc[j] * rkc);
    tw = fmaf(m, m, tw);
  }
#pragma unroll
  for (int m = 32; m; m >>= 1) tw += __shfl_xor(tw, m);
  if (lane == 0) red[20 + wave] = tw;
  __syncthreads();
  if (t == 0){
    float twt = red[20] + red[21] + red[22] + red[23];
    out[r] = 0.5f * tanhf(sqrtf(twt)) + 0.5f * (dtot * (1.f / 512.f));
  }
}

extern "C" void kernel_launch(void* const* d_in, const int* in_sizes, int n_in,
                              void* d_out, int out_size, void* d_ws, size_t ws_size,
                              hipStream_t stream)
{
  const float* x       = (const float*)d_in[0];
  const float* gate_W  = (const float*)d_in[1];
  const float* gate_b  = (const float*)d_in[2];
  const float* mag_W   = (const float*)d_in[3];
  const float* mag_b   = (const float*)d_in[4];
  const float* Wq      = (const float*)d_in[5];
  const float* Wk      = (const float*)d_in[6];
  const float* phase_W = (const float*)d_in[7];
  float* out = (float*)d_out;

  char* ws = (char*)d_ws;
  unsigned short* xbf = (unsigned short*)ws;                  // 32 MB @0 (reused as xg)
  unsigned short* wbf = (unsigned short*)(ws + 33554432);     // 10 MB @32M: [gate;mag;q;k;phase]
  float*          gate_pre = (float*)(ws + 46137344);         // 64 MB @44M (reused as q_pre bf16)
  unsigned short* mag_pre  = (unsigned short*)(ws + 113246208); // 32 MB @108M (reused as k_pre)
  unsigned short* p_pre    = (unsigned short*)(ws + 146800640); // 32 MB @140M
  unsigned short* q_pre = (unsigned short*)gate_pre;
  unsigned short* k_pre = mag_pre;

  dim3 b256(256);
  cvt_k<<<16384, b256, 0, stream>>>(x, xbf, ROWS * DIM);
  cvt_w<<<dim3(1024, 5), b256, 0, stream>>>(gate_W, mag_W, Wq, Wk, phase_W, wbf);

  // gate+mag fused GEMM (N=2048): seg0 = gate fp32, seg1 = mag bf16
  gemm_bt<<<dim3(16, 128), b256, 0, stream>>>(xbf, wbf, gate_b, mag_b,
                                              gate_pre, mag_pre, nullptr, 0b010);

  unsigned short* xg = xbf;   // xbf no longer needed
  select_k<<<ROWS, b256, 0, stream>>>(gate_pre, mag_pre, x, gate_W, gate_b, xg);

  // q+k+phase fused GEMM (N=3072), all bf16 out
  gemm_bt<<<dim3(24, 128), b256, 0, stream>>>(xg, wbf + (2u << 20), nullptr, nullptr,
                                              q_pre, k_pre, p_pre, 0b111);

  epilogue_k<<<ROWS, b256, 0, stream>>>(q_pre, k_pre, p_pre, out);
}